// Round 1
// baseline (523.774 us; speedup 1.0000x reference)
//
#include <hip/hip_runtime.h>
#include <math.h>

#define B_    64
#define T_    2048
#define DRNN  1024
#define DEMB  512
#define DATT  128
#define NF    32
#define KS    31
#define PADL  15
#define MP    64   // padded row pitch for merged conv matrix M

__device__ __forceinline__ float fast_tanh(float x){
    // tanh(x) = 1 - 2/(exp(2x)+1); saturates correctly for |x| large.
    float e2 = __expf(2.0f * x);
    return 1.0f - 2.0f / (e2 + 1.0f);
}

// ---------------------------------------------------------------------------
// K1: pq[b,a] = hidden[b,:] . Wq[a,:]   (blocks 0..63)
//     M[a, c*31+k] = sum_f Wd[a,f]*conv_w[f,c,k]   (block 64)
// ---------------------------------------------------------------------------
__global__ __launch_bounds__(128) void prep_kernel(
    const float* __restrict__ hidden, const float* __restrict__ Wq,
    const float* __restrict__ Wd, const float* __restrict__ convw,
    float* __restrict__ pq, float* __restrict__ M)
{
    const int blk = blockIdx.x;
    const int a = threadIdx.x;   // 128 threads
    if (blk < B_) {
        __shared__ float sh[DRNN];
        const int b = blk;
        #pragma unroll
        for (int i = 0; i < DRNN/128; ++i) sh[a + 128*i] = hidden[b*DRNN + a + 128*i];
        __syncthreads();
        const float4* wq4 = (const float4*)(Wq + a*DRNN);
        float acc = 0.f;
        #pragma unroll 4
        for (int k = 0; k < DRNN/4; ++k){
            float4 w = wq4[k];
            acc = fmaf(w.x, sh[4*k+0], acc);
            acc = fmaf(w.y, sh[4*k+1], acc);
            acc = fmaf(w.z, sh[4*k+2], acc);
            acc = fmaf(w.w, sh[4*k+3], acc);
        }
        pq[b*DATT + a] = acc;
    } else {
        float wd[NF];
        #pragma unroll
        for (int f = 0; f < NF; ++f) wd[f] = Wd[a*NF + f];
        for (int ck = 0; ck < 2*KS; ++ck){
            float acc = 0.f;
            #pragma unroll
            for (int f = 0; f < NF; ++f) acc = fmaf(wd[f], convw[f*2*KS + ck], acc);
            M[a*MP + ck] = acc;
        }
    }
}

// ---------------------------------------------------------------------------
// K2: e[b,t] = sum_a Wv[a] * tanh(pq[b,a] + paw[b,t,a] + pm[b,t,a])
//     paw via merged M: paw = sum_{c,k} M[a,c*31+k] * aw[b,c,t+k-15]
//     lane = t; aw window lives in 62 registers; M/pq/Wv are wave-uniform.
// ---------------------------------------------------------------------------
__global__ __launch_bounds__(256) void energy_kernel(
    const float* __restrict__ pm, const float* __restrict__ awcat,
    const float* __restrict__ pq, const float* __restrict__ M,
    const float* __restrict__ Wv, float* __restrict__ evec)
{
    const int b  = blockIdx.y;
    const int t0 = blockIdx.x * 256;
    const int tid = threadIdx.x;

    __shared__ float saw0[256 + 2*PADL];
    __shared__ float saw1[256 + 2*PADL];
    for (int i = tid; i < 256 + 2*PADL; i += 256){
        int tt = t0 - PADL + i;
        bool ok = (tt >= 0) && (tt < T_);
        saw0[i] = ok ? awcat[(b*2+0)*T_ + tt] : 0.f;
        saw1[i] = ok ? awcat[(b*2+1)*T_ + tt] : 0.f;
    }
    __syncthreads();

    float aw0[KS], aw1[KS];
    #pragma unroll
    for (int k = 0; k < KS; ++k){ aw0[k] = saw0[tid + k]; aw1[k] = saw1[tid + k]; }

    const int t = t0 + tid;
    const float4* pm4 = (const float4*)(pm + (size_t)(b*T_ + t) * DATT);
    float e = 0.f;
    #pragma unroll 2
    for (int a4 = 0; a4 < DATT/4; ++a4){
        float4 p = pm4[a4];
        float pv[4] = {p.x, p.y, p.z, p.w};
        #pragma unroll
        for (int u = 0; u < 4; ++u){
            const int a = 4*a4 + u;
            const float* Ma = M + a*MP;           // uniform address -> s_load
            float x = pq[b*DATT + a] + pv[u];
            #pragma unroll
            for (int k = 0; k < KS; ++k) x = fmaf(Ma[k],      aw0[k], x);
            #pragma unroll
            for (int k = 0; k < KS; ++k) x = fmaf(Ma[KS + k], aw1[k], x);
            e = fmaf(Wv[a], fast_tanh(x), e);
        }
    }
    evec[b*T_ + t] = e;
}

// ---------------------------------------------------------------------------
// K3: per-b masked softmax stats: mx = max over unmasked, rinv = 1/sum(exp)
// ---------------------------------------------------------------------------
__global__ __launch_bounds__(256) void stats_kernel(
    const float* __restrict__ evec, const int* __restrict__ mask,
    float* __restrict__ stats)
{
    const int b = blockIdx.x;
    const int tid = threadIdx.x;
    float ev[T_/256]; int mk[T_/256];
    float mx = -INFINITY;
    #pragma unroll
    for (int i = 0; i < T_/256; ++i){
        int t = tid + 256*i;
        ev[i] = evec[b*T_ + t];
        mk[i] = mask[b*T_ + t];
        if (!mk[i]) mx = fmaxf(mx, ev[i]);
    }
    #pragma unroll
    for (int off = 1; off < 64; off <<= 1) mx = fmaxf(mx, __shfl_xor(mx, off, 64));
    __shared__ float sred[4];
    const int wid = tid >> 6, lane = tid & 63;
    if (lane == 0) sred[wid] = mx;
    __syncthreads();
    mx = fmaxf(fmaxf(sred[0], sred[1]), fmaxf(sred[2], sred[3]));

    float s = 0.f;
    #pragma unroll
    for (int i = 0; i < T_/256; ++i) if (!mk[i]) s += __expf(ev[i] - mx);
    #pragma unroll
    for (int off = 1; off < 64; off <<= 1) s += __shfl_xor(s, off, 64);
    __shared__ float ssum[4];
    if (lane == 0) ssum[wid] = s;
    __syncthreads();
    if (tid == 0){
        float tot = ssum[0] + ssum[1] + ssum[2] + ssum[3];
        stats[2*b]   = mx;
        stats[2*b+1] = 1.0f / tot;
    }
}

// ---------------------------------------------------------------------------
// K4: weights out + context = sum_t w[b,t]*memory[b,t,:]  (atomic partials)
// ---------------------------------------------------------------------------
__global__ __launch_bounds__(256) void context_kernel(
    const float* __restrict__ evec, const int* __restrict__ mask,
    const float* __restrict__ stats, const float* __restrict__ memory,
    float* __restrict__ ctx, float* __restrict__ wout)
{
    const int b  = blockIdx.y;
    const int t0 = blockIdx.x * 256;
    const int tid = threadIdx.x;
    __shared__ float sw[256];

    const float mx = stats[2*b], rinv = stats[2*b+1];
    {
        const int t = t0 + tid;
        const float e = evec[b*T_ + t];
        const int mk = mask[b*T_ + t];
        const float w = mk ? 0.f : __expf(e - mx) * rinv;
        sw[tid] = w;
        wout[b*T_ + t] = w;
    }
    __syncthreads();

    float2 acc = make_float2(0.f, 0.f);
    const float2* mem2 = (const float2*)(memory + (size_t)(b*T_ + t0) * DEMB) + tid;
    #pragma unroll 4
    for (int tt = 0; tt < 256; ++tt){
        const float w = sw[tt];
        const float2 m = mem2[(size_t)tt * (DEMB/2)];
        acc.x = fmaf(w, m.x, acc.x);
        acc.y = fmaf(w, m.y, acc.y);
    }
    atomicAdd(&ctx[b*DEMB + 2*tid + 0], acc.x);
    atomicAdd(&ctx[b*DEMB + 2*tid + 1], acc.y);
}

// ---------------------------------------------------------------------------
extern "C" void kernel_launch(void* const* d_in, const int* in_sizes, int n_in,
                              void* d_out, int out_size, void* d_ws, size_t ws_size,
                              hipStream_t stream)
{
    const float* hidden = (const float*)d_in[0];   // (B, D_RNN)
    const float* memory = (const float*)d_in[1];   // (B, T, D_EMB)
    const float* pm     = (const float*)d_in[2];   // (B, T, D_ATT)
    const float* awcat  = (const float*)d_in[3];   // (B, 2, T)
    const int*   mask   = (const int*)d_in[4];     // (B, T)
    const float* Wq     = (const float*)d_in[5];   // (D_ATT, D_RNN)
    const float* Wv     = (const float*)d_in[6];   // (1, D_ATT)
    const float* convw  = (const float*)d_in[7];   // (NF, 2, KS)
    const float* Wd     = (const float*)d_in[8];   // (D_ATT, NF)

    float* out  = (float*)d_out;
    float* ctx  = out;               // (B, D_EMB)
    float* wout = out + B_*DEMB;     // (B, T)

    float* pq    = (float*)d_ws;            // B*DATT
    float* M     = pq + B_*DATT;            // DATT*MP
    float* ev    = M + DATT*MP;             // B*T
    float* stats = ev + B_*T_;              // 2*B

    hipMemsetAsync(ctx, 0, B_*DEMB*sizeof(float), stream);

    prep_kernel<<<dim3(B_ + 1), 128, 0, stream>>>(hidden, Wq, Wd, convw, pq, M);
    energy_kernel<<<dim3(T_/256, B_), 256, 0, stream>>>(pm, awcat, pq, M, Wv, ev);
    stats_kernel<<<dim3(B_), 256, 0, stream>>>(ev, mask, stats);
    context_kernel<<<dim3(T_/256, B_), 256, 0, stream>>>(ev, mask, stats, memory, ctx, wout);
}

// Round 2
// 488.786 us; speedup vs baseline: 1.0716x; 1.0716x over previous
//
#include <hip/hip_runtime.h>
#include <math.h>

#define B_    64
#define T_    2048
#define DRNN  1024
#define DEMB  512
#define DATT  128
#define NF    32
#define KS    31
#define PADL  15
#define MP    64   // padded row pitch for merged conv matrix M
#define TT    32   // t's per thread in energy kernel

__device__ __forceinline__ float fast_tanh(float x){
    float e2 = __expf(2.0f * x);
    return 1.0f - 2.0f / (e2 + 1.0f);
}

// ---------------------------------------------------------------------------
// K1: pq[b,a] = hidden[b,:] . Wq[a,:]   (blocks 0..63)
//     M[a, c*31+k] = sum_f Wd[a,f]*conv_w[f,c,k]   (block 64)
// ---------------------------------------------------------------------------
__global__ __launch_bounds__(128) void prep_kernel(
    const float* __restrict__ hidden, const float* __restrict__ Wq,
    const float* __restrict__ Wd, const float* __restrict__ convw,
    float* __restrict__ pq, float* __restrict__ M)
{
    const int blk = blockIdx.x;
    const int a = threadIdx.x;   // 128 threads
    if (blk < B_) {
        __shared__ float sh[DRNN];
        const int b = blk;
        #pragma unroll
        for (int i = 0; i < DRNN/128; ++i) sh[a + 128*i] = hidden[b*DRNN + a + 128*i];
        __syncthreads();
        const float4* wq4 = (const float4*)(Wq + a*DRNN);
        float acc = 0.f;
        #pragma unroll 4
        for (int k = 0; k < DRNN/4; ++k){
            float4 w = wq4[k];
            acc = fmaf(w.x, sh[4*k+0], acc);
            acc = fmaf(w.y, sh[4*k+1], acc);
            acc = fmaf(w.z, sh[4*k+2], acc);
            acc = fmaf(w.w, sh[4*k+3], acc);
        }
        pq[b*DATT + a] = acc;
    } else {
        float wd[NF];
        #pragma unroll
        for (int f = 0; f < NF; ++f) wd[f] = Wd[a*NF + f];
        for (int ck = 0; ck < 2*KS; ++ck){
            float acc = 0.f;
            #pragma unroll
            for (int f = 0; f < NF; ++f) acc = fmaf(wd[f], convw[f*2*KS + ck], acc);
            M[a*MP + ck] = acc;
        }
    }
}

// ---------------------------------------------------------------------------
// K2 (energy v2): lane = a. Each thread holds its M row (62 regs) and TT=32
// accumulators; aw values broadcast from LDS; ALL hot-loop FMAs are
// register-register. Cross-lane (over a=128) reduction via shfl + LDS.
// Also emits per-64t-chunk softmax partials (pmax, psum) -> no stats kernel.
// Grid: x = T_/64 = 32, y = B. Block = 256: tile s = tid>>7 covers 32 t's.
// ---------------------------------------------------------------------------
__global__ __launch_bounds__(256) void energy_kernel(
    const float* __restrict__ pm, const float* __restrict__ awcat,
    const float* __restrict__ pq, const float* __restrict__ M,
    const float* __restrict__ Wv, const int* __restrict__ mask,
    float* __restrict__ ev, float* __restrict__ pmax, float* __restrict__ psum)
{
    const int b   = blockIdx.y;
    const int t0  = blockIdx.x * 64;     // block covers [t0, t0+64)
    const int tid = threadIdx.x;
    const int s   = tid >> 7;            // tile 0/1
    const int a   = tid & 127;
    const int ts  = t0 + TT * s;         // this tile's first t

    __shared__ float saw0[96], saw1[96];     // aw[c, t0-15 .. t0+78]
    __shared__ float sred[2][2][TT];         // [tile][a-half][t]

    for (int i = tid; i < 94; i += 256){
        int tt = t0 - PADL + i;
        bool ok = (tt >= 0) && (tt < T_);
        saw0[i] = ok ? awcat[(b*2+0)*T_ + tt] : 0.f;
        saw1[i] = ok ? awcat[(b*2+1)*T_ + tt] : 0.f;
    }
    __syncthreads();

    // M row -> registers (L2-resident, tiny)
    float Ma0[KS], Ma1[KS];
    const float* Mrow = M + a*MP;
    #pragma unroll
    for (int k = 0; k < KS; ++k){ Ma0[k] = Mrow[k]; Ma1[k] = Mrow[KS + k]; }
    const float pqa = pq[b*DATT + a];
    const float wv  = Wv[a];

    float acc[TT];
    #pragma unroll
    for (int t = 0; t < TT; ++t) acc[t] = pqa;

    // FIR over broadcast aw: j = tile-local aw index in [0, TT+KS-2]
    #pragma unroll
    for (int j = 0; j < TT + KS - 1; ++j){
        const float av0 = saw0[j + TT*s];
        const float av1 = saw1[j + TT*s];
        const int tlo = (j - KS + 1) > 0 ? (j - KS + 1) : 0;
        const int thi = (j < TT - 1) ? j : (TT - 1);
        #pragma unroll
        for (int t = tlo; t <= thi; ++t){
            acc[t] = fmaf(Ma0[j - t], av0, acc[t]);
            acc[t] = fmaf(Ma1[j - t], av1, acc[t]);
        }
    }

    // + pm, tanh, * Wv  (pm coalesced over a)
    const float* pmb = pm + ((size_t)(b*T_ + ts)) * DATT + a;
    #pragma unroll
    for (int t = 0; t < TT; ++t){
        float x = acc[t] + pmb[(size_t)t * DATT];
        acc[t] = wv * fast_tanh(x);
    }

    // reduce over a (64-lane butterfly, then combine two halves via LDS)
    const int lane = tid & 63;
    const int half = a >> 6;
    #pragma unroll
    for (int t = 0; t < TT; ++t){
        float r = acc[t];
        r += __shfl_xor(r, 1, 64);  r += __shfl_xor(r, 2, 64);
        r += __shfl_xor(r, 4, 64);  r += __shfl_xor(r, 8, 64);
        r += __shfl_xor(r, 16, 64); r += __shfl_xor(r, 32, 64);
        if (lane == 0) sred[s][half][t] = r;
    }
    __syncthreads();

    // threads 0..63 finalize the block's 64 energies + softmax partials
    if (tid < 64){
        const int tile = tid >> 5, tl = tid & 31;
        const int t = t0 + tid;
        float e = sred[tile][0][tl] + sred[tile][1][tl];
        const int mk = mask[b*T_ + t];
        if (mk) e = -INFINITY;
        ev[b*T_ + t] = e;
        float mval = mk ? -1e30f : e;
        #pragma unroll
        for (int off = 1; off < 64; off <<= 1) mval = fmaxf(mval, __shfl_xor(mval, off, 64));
        float sv = mk ? 0.f : __expf(e - mval);
        #pragma unroll
        for (int off = 1; off < 64; off <<= 1) sv += __shfl_xor(sv, off, 64);
        if (tid == 0){
            pmax[b*32 + blockIdx.x] = mval;
            psum[b*32 + blockIdx.x] = sv;
        }
    }
}

// ---------------------------------------------------------------------------
// K3 (context v2): combine softmax partials in-block, write weights, then
// float4-stream memory with deep unroll; LDS pre-reduce then atomic partials.
// Grid: x = T_/256 = 8, y = B.
// ---------------------------------------------------------------------------
__global__ __launch_bounds__(256) void context_kernel(
    const float* __restrict__ ev, const float* __restrict__ pmax,
    const float* __restrict__ psum, const float* __restrict__ memory,
    float* __restrict__ ctx, float* __restrict__ wout)
{
    const int b   = blockIdx.y;
    const int t0  = blockIdx.x * 256;
    const int tid = threadIdx.x;
    __shared__ float sw[256];
    __shared__ float sstat[2];
    __shared__ float4 sacc[128];

    if (tid < 64){
        float pmv = (tid < 32) ? pmax[b*32 + tid] : -1e30f;
        float psv = (tid < 32) ? psum[b*32 + tid] : 0.f;
        float g = pmv;
        #pragma unroll
        for (int off = 1; off < 64; off <<= 1) g = fmaxf(g, __shfl_xor(g, off, 64));
        float c = psv * __expf(pmv - g);
        #pragma unroll
        for (int off = 1; off < 64; off <<= 1) c += __shfl_xor(c, off, 64);
        if (tid == 0){ sstat[0] = g; sstat[1] = 1.0f / c; }
    }
    __syncthreads();
    const float gmax = sstat[0], rinv = sstat[1];
    {
        const int t = t0 + tid;
        const float e = ev[b*T_ + t];
        const float w = __expf(e - gmax) * rinv;   // e = -inf  ->  w = 0
        sw[tid] = w;
        wout[b*T_ + t] = w;
    }
    __syncthreads();

    const int col = tid & 127;   // float4 column within the 512-float row
    const int row = tid >> 7;    // 0/1: interleaved t's
    float4 acc = make_float4(0.f, 0.f, 0.f, 0.f);
    const float4* mem4 = (const float4*)memory + ((size_t)(b*T_ + t0))*(DEMB/4) + col;
    #pragma unroll 8
    for (int tt = row; tt < 256; tt += 2){
        const float w = sw[tt];
        const float4 m = mem4[(size_t)tt * (DEMB/4)];
        acc.x = fmaf(w, m.x, acc.x);
        acc.y = fmaf(w, m.y, acc.y);
        acc.z = fmaf(w, m.z, acc.z);
        acc.w = fmaf(w, m.w, acc.w);
    }
    if (row == 1) sacc[col] = acc;
    __syncthreads();
    if (row == 0){
        const float4 o = sacc[col];
        atomicAdd(&ctx[b*DEMB + 4*col + 0], acc.x + o.x);
        atomicAdd(&ctx[b*DEMB + 4*col + 1], acc.y + o.y);
        atomicAdd(&ctx[b*DEMB + 4*col + 2], acc.z + o.z);
        atomicAdd(&ctx[b*DEMB + 4*col + 3], acc.w + o.w);
    }
}

// ---------------------------------------------------------------------------
extern "C" void kernel_launch(void* const* d_in, const int* in_sizes, int n_in,
                              void* d_out, int out_size, void* d_ws, size_t ws_size,
                              hipStream_t stream)
{
    const float* hidden = (const float*)d_in[0];   // (B, D_RNN)
    const float* memory = (const float*)d_in[1];   // (B, T, D_EMB)
    const float* pm     = (const float*)d_in[2];   // (B, T, D_ATT)
    const float* awcat  = (const float*)d_in[3];   // (B, 2, T)
    const int*   mask   = (const int*)d_in[4];     // (B, T)
    const float* Wq     = (const float*)d_in[5];   // (D_ATT, D_RNN)
    const float* Wv     = (const float*)d_in[6];   // (1, D_ATT)
    const float* convw  = (const float*)d_in[7];   // (NF, 2, KS)
    const float* Wd     = (const float*)d_in[8];   // (D_ATT, NF)

    float* out  = (float*)d_out;
    float* ctx  = out;               // (B, D_EMB)
    float* wout = out + B_*DEMB;     // (B, T)

    float* pq    = (float*)d_ws;            // B*DATT
    float* M     = pq + B_*DATT;            // DATT*MP
    float* ev    = M + DATT*MP;             // B*T
    float* pmax  = ev + B_*T_;              // B*32
    float* psum  = pmax + B_*32;            // B*32

    hipMemsetAsync(ctx, 0, B_*DEMB*sizeof(float), stream);

    prep_kernel<<<dim3(B_ + 1), 128, 0, stream>>>(hidden, Wq, Wd, convw, pq, M);
    energy_kernel<<<dim3(T_/64, B_), 256, 0, stream>>>(pm, awcat, pq, M, Wv, mask, ev, pmax, psum);
    context_kernel<<<dim3(T_/256, B_), 256, 0, stream>>>(ev, pmax, psum, memory, ctx, wout);
}

// Round 3
// 484.188 us; speedup vs baseline: 1.0818x; 1.0095x over previous
//
#include <hip/hip_runtime.h>
#include <math.h>

#define B_    64
#define T_    2048
#define DRNN  1024
#define DEMB  512
#define DATT  128
#define NF    32
#define KS    31
#define PADL  15
#define MP    64   // padded row pitch for merged conv matrix M
#define TT    32   // t's per thread-tile in energy phase
#define CT    64   // t's per block (chunk)
#define NC    (T_/CT)   // 32 chunks per batch row

__device__ __forceinline__ float fast_tanh(float x){
    float e2 = __expf(2.0f * x);
    return 1.0f - 2.0f / (e2 + 1.0f);
}

// ---------------------------------------------------------------------------
// K1: pq[b,a] = hidden[b,:] . Wq[a,:]   (blocks 0..63)
//     M[a, c*31+k] = sum_f Wd[a,f]*conv_w[f,c,k]   (block 64)
// ---------------------------------------------------------------------------
__global__ __launch_bounds__(128) void prep_kernel(
    const float* __restrict__ hidden, const float* __restrict__ Wq,
    const float* __restrict__ Wd, const float* __restrict__ convw,
    float* __restrict__ pq, float* __restrict__ M)
{
    const int blk = blockIdx.x;
    const int a = threadIdx.x;   // 128 threads
    if (blk < B_) {
        __shared__ float sh[DRNN];
        const int b = blk;
        #pragma unroll
        for (int i = 0; i < DRNN/128; ++i) sh[a + 128*i] = hidden[b*DRNN + a + 128*i];
        __syncthreads();
        const float4* wq4 = (const float4*)(Wq + a*DRNN);
        float acc = 0.f;
        #pragma unroll 4
        for (int k = 0; k < DRNN/4; ++k){
            float4 w = wq4[k];
            acc = fmaf(w.x, sh[4*k+0], acc);
            acc = fmaf(w.y, sh[4*k+1], acc);
            acc = fmaf(w.z, sh[4*k+2], acc);
            acc = fmaf(w.w, sh[4*k+3], acc);
        }
        pq[b*DATT + a] = acc;
    } else {
        float wd[NF];
        #pragma unroll
        for (int f = 0; f < NF; ++f) wd[f] = Wd[a*NF + f];
        for (int ck = 0; ck < 2*KS; ++ck){
            float acc = 0.f;
            #pragma unroll
            for (int f = 0; f < NF; ++f) acc = fmaf(wd[f], convw[f*2*KS + ck], acc);
            M[a*MP + ck] = acc;
        }
    }
}

// ---------------------------------------------------------------------------
// K2 (fused energy + chunk-softmax + partial context), flash-attention style.
// Grid: x = NC (=32 chunks of 64 t), y = B. Block = 256.
// Phase 1: lane=a energy (register FIR over merged conv matrix M).
// Phase 2: chunk-local softmax partials m_c, s_c, p_t = exp(e_t - m_c).
// Phase 3: pctx_c[d] = sum_t p_t * mem[t,d]; rows with p_t==0 (masked) are
//          skipped via a WAVE-UNIFORM branch (sp[] broadcast) -> ~halves
//          the dominant memory traffic.
// ---------------------------------------------------------------------------
__global__ __launch_bounds__(256) void fused_kernel(
    const float* __restrict__ pm, const float* __restrict__ awcat,
    const float* __restrict__ pq, const float* __restrict__ M,
    const float* __restrict__ Wv, const int* __restrict__ mask,
    const float* __restrict__ memory,
    float* __restrict__ pbuf, float* __restrict__ pmax,
    float* __restrict__ psum, float* __restrict__ pctx)
{
    const int b   = blockIdx.y;
    const int cx  = blockIdx.x;
    const int t0  = cx * CT;             // block covers [t0, t0+64)
    const int tid = threadIdx.x;
    const int s   = tid >> 7;            // tile 0/1
    const int a   = tid & 127;
    const int ts  = t0 + TT * s;

    __shared__ float saw0[96], saw1[96];     // aw[c, t0-15 .. t0+78]
    __shared__ float sred[2][2][TT];         // [tile][a-half][t]
    __shared__ float sp[CT];                 // p_t for phase 3
    __shared__ float4 sacc[128];

    for (int i = tid; i < 94; i += 256){
        int tt = t0 - PADL + i;
        bool ok = (tt >= 0) && (tt < T_);
        saw0[i] = ok ? awcat[(b*2+0)*T_ + tt] : 0.f;
        saw1[i] = ok ? awcat[(b*2+1)*T_ + tt] : 0.f;
    }
    __syncthreads();

    // ---- Phase 1: energies ----
    float Ma0[KS], Ma1[KS];
    const float* Mrow = M + a*MP;
    #pragma unroll
    for (int k = 0; k < KS; ++k){ Ma0[k] = Mrow[k]; Ma1[k] = Mrow[KS + k]; }
    const float pqa = pq[b*DATT + a];
    const float wv  = Wv[a];

    float acc[TT];
    #pragma unroll
    for (int t = 0; t < TT; ++t) acc[t] = pqa;

    #pragma unroll
    for (int j = 0; j < TT + KS - 1; ++j){
        const float av0 = saw0[j + TT*s];
        const float av1 = saw1[j + TT*s];
        const int tlo = (j - KS + 1) > 0 ? (j - KS + 1) : 0;
        const int thi = (j < TT - 1) ? j : (TT - 1);
        #pragma unroll
        for (int t = tlo; t <= thi; ++t){
            acc[t] = fmaf(Ma0[j - t], av0, acc[t]);
            acc[t] = fmaf(Ma1[j - t], av1, acc[t]);
        }
    }

    const float* pmb = pm + ((size_t)(b*T_ + ts)) * DATT + a;
    #pragma unroll
    for (int t = 0; t < TT; ++t){
        float x = acc[t] + pmb[(size_t)t * DATT];
        acc[t] = wv * fast_tanh(x);
    }

    const int lane = tid & 63;
    const int half = a >> 6;
    #pragma unroll
    for (int t = 0; t < TT; ++t){
        float r = acc[t];
        r += __shfl_xor(r, 1, 64);  r += __shfl_xor(r, 2, 64);
        r += __shfl_xor(r, 4, 64);  r += __shfl_xor(r, 8, 64);
        r += __shfl_xor(r, 16, 64); r += __shfl_xor(r, 32, 64);
        if (lane == 0) sred[s][half][t] = r;
    }
    __syncthreads();

    // ---- Phase 2: chunk softmax partials (single wave, 64 t's) ----
    if (tid < 64){
        const int t = t0 + tid;
        float e = sred[tid>>5][0][tid&31] + sred[tid>>5][1][tid&31];
        const int mk = mask[b*T_ + t];
        float mval = mk ? -1e30f : e;
        #pragma unroll
        for (int off = 1; off < 64; off <<= 1) mval = fmaxf(mval, __shfl_xor(mval, off, 64));
        const float pval = mk ? 0.f : __expf(e - mval);
        float sv = pval;
        #pragma unroll
        for (int off = 1; off < 64; off <<= 1) sv += __shfl_xor(sv, off, 64);
        sp[tid] = pval;
        pbuf[b*T_ + t] = pval;
        if (tid == 0){
            pmax[b*NC + cx] = mval;
            psum[b*NC + cx] = sv;
        }
    }
    __syncthreads();

    // ---- Phase 3: partial context, skipping masked rows (uniform branch) ----
    const int col = tid & 127;   // float4 column (DEMB/4 = 128)
    const int row = tid >> 7;    // 2 t's in flight
    float4 a4 = make_float4(0.f, 0.f, 0.f, 0.f);
    const float4* mem4 = (const float4*)memory + ((size_t)(b*T_ + t0))*(DEMB/4) + col;
    for (int tt = row; tt < CT; tt += 2){
        const float w = sp[tt];          // wave-uniform (LDS broadcast)
        if (w != 0.f){
            const float4 m = mem4[(size_t)tt * (DEMB/4)];
            a4.x = fmaf(w, m.x, a4.x);
            a4.y = fmaf(w, m.y, a4.y);
            a4.z = fmaf(w, m.z, a4.z);
            a4.w = fmaf(w, m.w, a4.w);
        }
    }
    if (row == 1) sacc[col] = a4;
    __syncthreads();
    if (row == 0){
        const float4 o = sacc[col];
        float4* dst = (float4*)(pctx + ((size_t)(b*NC + cx))*DEMB) + col;
        *dst = make_float4(a4.x + o.x, a4.y + o.y, a4.z + o.z, a4.w + o.w);
    }
}

// ---------------------------------------------------------------------------
// K3 (finalize): per b — global max/Z from chunk partials, then
//   ctx[d]  = sum_c scale_c * pctx_c[d],  scale_c = exp(m_c - g)/Z
//   w[t]    = p[t] * scale_{c(t)}
// ---------------------------------------------------------------------------
__global__ __launch_bounds__(256) void finalize_kernel(
    const float* __restrict__ pbuf, const float* __restrict__ pmax,
    const float* __restrict__ psum, const float* __restrict__ pctx,
    float* __restrict__ ctx, float* __restrict__ wout)
{
    const int b = blockIdx.x;
    const int tid = threadIdx.x;
    __shared__ float sscale[NC];

    if (tid < 64){
        float mv = (tid < NC) ? pmax[b*NC + tid] : -1e30f;
        float sv = (tid < NC) ? psum[b*NC + tid] : 0.f;
        float g = mv;
        #pragma unroll
        for (int off = 1; off < 64; off <<= 1) g = fmaxf(g, __shfl_xor(g, off, 64));
        float z = sv * __expf(mv - g);
        #pragma unroll
        for (int off = 1; off < 64; off <<= 1) z += __shfl_xor(z, off, 64);
        if (tid < NC) sscale[tid] = __expf(mv - g) / z;
    }
    __syncthreads();

    // ctx: 256 threads x float2 = 512 d's
    float2 a2 = make_float2(0.f, 0.f);
    const float2* pc2 = (const float2*)(pctx + (size_t)b*NC*DEMB) + tid;
    #pragma unroll
    for (int c = 0; c < NC; ++c){
        const float sc = sscale[c];
        if (sc != 0.f){
            const float2 v = pc2[(size_t)c * (DEMB/2)];
            a2.x = fmaf(sc, v.x, a2.x);
            a2.y = fmaf(sc, v.y, a2.y);
        }
    }
    ((float2*)(ctx + b*DEMB))[tid] = a2;

    // weights
    #pragma unroll
    for (int i = 0; i < T_/256; ++i){
        const int t = tid + 256*i;
        wout[b*T_ + t] = pbuf[b*T_ + t] * sscale[t >> 6];
    }
}

// ---------------------------------------------------------------------------
extern "C" void kernel_launch(void* const* d_in, const int* in_sizes, int n_in,
                              void* d_out, int out_size, void* d_ws, size_t ws_size,
                              hipStream_t stream)
{
    const float* hidden = (const float*)d_in[0];   // (B, D_RNN)
    const float* memory = (const float*)d_in[1];   // (B, T, D_EMB)
    const float* pm     = (const float*)d_in[2];   // (B, T, D_ATT)
    const float* awcat  = (const float*)d_in[3];   // (B, 2, T)
    const int*   mask   = (const int*)d_in[4];     // (B, T)
    const float* Wq     = (const float*)d_in[5];   // (D_ATT, D_RNN)
    const float* Wv     = (const float*)d_in[6];   // (1, D_ATT)
    const float* convw  = (const float*)d_in[7];   // (NF, 2, KS)
    const float* Wd     = (const float*)d_in[8];   // (D_ATT, NF)

    float* out  = (float*)d_out;
    float* ctx  = out;               // (B, D_EMB)
    float* wout = out + B_*DEMB;     // (B, T)

    float* pq    = (float*)d_ws;             // 8192
    float* M     = pq   + B_*DATT;           // 8192
    float* pbuf  = M    + DATT*MP;           // B*T = 131072
    float* pmax  = pbuf + B_*T_;             // B*NC = 2048
    float* psum  = pmax + B_*NC;             // 2048
    float* pctx  = psum + B_*NC;             // B*NC*DEMB = 4 MB

    prep_kernel<<<dim3(B_ + 1), 128, 0, stream>>>(hidden, Wq, Wd, convw, pq, M);
    fused_kernel<<<dim3(NC, B_), 256, 0, stream>>>(pm, awcat, pq, M, Wv, mask,
                                                   memory, pbuf, pmax, psum, pctx);
    finalize_kernel<<<dim3(B_), 256, 0, stream>>>(pbuf, pmax, psum, pctx, ctx, wout);
}